// Round 2
// baseline (870.734 us; speedup 1.0000x reference)
//
#include <hip/hip_runtime.h>
#include <stdint.h>

#define NC   8
#define NK   4096
#define DD   128
#define NCLS 1000
#define NB   8192

// ---------------------------------------------------------------------------
// d_out byte layout during the run (out buffer = 32,768,000 B total):
//   [0,          16,777,216)  bimg : prepped f16 hi/lo codebook images
//   [16,777,216, 16,908,288)  csq  : f32 ||c||^2  (8*4096)
//   [17,200,000, 17,462,144)  P    : packed top-2 (u16|u16) per (b,k)
//                                    = u32 index 4,300,000.. (rows 4300..4365)
//   reloc_* copy each row's 8 packed u32s into that row's first 32 bytes.
//   finish reads ONLY its own row header, then overwrites the full row.
//   d_ws is never used (ws_size may be 0 — round-1 OOB corruption fix).
// ---------------------------------------------------------------------------
#define CSQ_F32   4194304
#define P_U32     4300000
#define TAIL_LO   4300
#define TAIL_HI   4366

typedef _Float16 f16;
typedef f16   f16x8 __attribute__((ext_vector_type(8)));
typedef float f32x4 __attribute__((ext_vector_type(4)));

typedef const __attribute__((address_space(1))) unsigned int g_u32;
typedef __attribute__((address_space(3))) unsigned int l_u32;

// async global->LDS, 16B per lane, wave-uniform LDS base + lane*16
__device__ __forceinline__ void gll16(const char* g, char* l) {
    __builtin_amdgcn_global_load_lds((g_u32*)g, (l_u32*)l, 16, 0, 0);
}

// XOR swizzle: image row-major [row][16 groups of 8 f16], 256B/row.
__device__ __forceinline__ int swz(int row, int kg) {
    return (row * 256 + kg * 16) ^ ((row & 7) << 4);
}

// insert candidate into running top-2, ties prefer lower index (np argmin)
__device__ __forceinline__ void ins(float cv, int ci, float& v1, int& i1,
                                    float& v2, int& i2) {
    const bool b1 = (cv > v1) || (cv == v1 && ci < i1);
    const bool b2 = (cv > v2) || (cv == v2 && ci < i2);
    if (b1) { v2 = v1; i2 = i1; v1 = cv; i1 = ci; }
    else if (b2) { v2 = cv; i2 = ci; }
}

// ---------------------------------------------------------------------------
// Kernel 1: split codebooks into f16 hi/lo pre-swizzled LDS images + csq.
// Image per (k, chunk of 64 codewords): 32KB = [hi 16KB][lo 16KB].
// lo parts scaled by 2048 to stay in f16 normal range.
// ---------------------------------------------------------------------------
__global__ __launch_bounds__(256) void prep_cb(const float* __restrict__ cb,
                                               char* __restrict__ bimg,
                                               float* __restrict__ csq) {
    const int chunk = blockIdx.x, k = blockIdx.y, t = threadIdx.x;
    const float* src = cb + ((size_t)k * NK + (size_t)chunk * 64) * DD;
    char* dst = bimg + (size_t)(k * 64 + chunk) * 32768;
#pragma unroll
    for (int j = 0; j < 4; ++j) {
        const int col = j * 16 + (t >> 4);
        const int kg  = t & 15;
        const float* p = src + (size_t)col * DD + kg * 8;
        const float4 v0 = *(const float4*)p;
        const float4 v1 = *(const float4*)(p + 4);
        float vs[8] = {v0.x, v0.y, v0.z, v0.w, v1.x, v1.y, v1.z, v1.w};
        f16x8 h, l;
        float ss = 0.f;
#pragma unroll
        for (int i = 0; i < 8; ++i) {
            const float v = vs[i];
            ss += v * v;
            const f16 hi = (f16)v;
            h[i] = hi;
            l[i] = (f16)((v - (float)hi) * 2048.0f);
        }
#pragma unroll
        for (int m = 1; m < 16; m <<= 1) ss += __shfl_xor(ss, m, 16);
        if (kg == 0) csq[k * NK + chunk * 64 + col] = ss;
        const int off = swz(col, kg);
        *(f16x8*)(dst + off)         = h;
        *(f16x8*)(dst + 16384 + off) = l;
    }
}

// ---------------------------------------------------------------------------
// Kernel 2: fused split-f16 MFMA distance GEMM + top-2 argmax of
// s = dot(x,c) - csq/2. Block: 128 rows x one codebook, 512 threads,
// 8 waves as 4 row-groups x 2 col-halves, wave-tile 32x32.
// ~180 VGPR -> 2 waves/SIMD; 64KB LDS -> 2 blocks/CU; grid 512 = 2/CU.
// ---------------------------------------------------------------------------
__global__ __launch_bounds__(512, 2) void gemm_argmin(
    const float* __restrict__ x, const char* __restrict__ bimg,
    const float* __restrict__ csq, uint32_t* __restrict__ pk) {
    __shared__ char lds[65536];
    const int t = threadIdx.x;
    const int lane = t & 63, w = t >> 6;
    const int bm = blockIdx.x, k = blockIdx.y;
    const int l15 = lane & 15, l4 = lane >> 4;
    const int wr = w >> 1, wc = w & 1;
    const int wm = wr * 32, wn = wc * 32;

    // ---- stage & split x tile: hi -> lds[0:32K), lo*2048 -> lds[32K:64K)
    {
        const float* xs = x + (size_t)bm * 128 * 1024 + k * DD;
#pragma unroll
        for (int j = 0; j < 4; ++j) {
            const int g = j * 512 + t;
            const int row = g >> 4, kg = g & 15;
            const float* p = xs + (size_t)row * 1024 + kg * 8;
            const float4 v0 = *(const float4*)p;
            const float4 v1 = *(const float4*)(p + 4);
            float vs[8] = {v0.x, v0.y, v0.z, v0.w, v1.x, v1.y, v1.z, v1.w};
            f16x8 h, l;
#pragma unroll
            for (int i = 0; i < 8; ++i) {
                const float v = vs[i];
                const f16 hi = (f16)v;
                h[i] = hi;
                l[i] = (f16)((v - (float)hi) * 2048.0f);
            }
            const int off = swz(row, kg);
            *(f16x8*)(lds + off)         = h;
            *(f16x8*)(lds + 32768 + off) = l;
        }
    }
    __syncthreads();

    f16x8 Ah[2][4], Al[2][4];
#pragma unroll
    for (int mi = 0; mi < 2; ++mi)
#pragma unroll
        for (int kk = 0; kk < 4; ++kk) {
            const int off = swz(wm + mi * 16 + l15, kk * 4 + l4);
            Ah[mi][kk] = *(const f16x8*)(lds + off);
            Al[mi][kk] = *(const f16x8*)(lds + 32768 + off);
        }
    __syncthreads();

    float rv1[2][4], rv2[2][4];
    int   ri1[2][4], ri2[2][4];
#pragma unroll
    for (int mi = 0; mi < 2; ++mi)
#pragma unroll
        for (int q = 0; q < 4; ++q) {
            rv1[mi][q] = -3.402823466e38f; rv2[mi][q] = -3.402823466e38f;
            ri1[mi][q] = 0; ri2[mi][q] = 0;
        }

    const char* gB = bimg + (size_t)k * 64 * 32768;
    // prologue: stage chunk 0 -> buf0 (lds[0:32K))
#pragma unroll
    for (int j = 0; j < 4; ++j)
        gll16(gB + j * 8192 + w * 1024 + lane * 16,
              lds + j * 8192 + w * 1024);
    asm volatile("s_waitcnt vmcnt(0)" ::: "memory");
    __syncthreads();

    for (int c = 0; c < 64; ++c) {
        const int cur = c & 1;
        char* bufc = lds + (cur ? 32768 : 0);
        if (c + 1 < 64) {  // stage next chunk into the other buffer
            const char* gs = gB + (size_t)(c + 1) * 32768;
            char* bufn = lds + (cur ? 0 : 32768);
#pragma unroll
            for (int j = 0; j < 4; ++j)
                gll16(gs + j * 8192 + w * 1024 + lane * 16,
                      bufn + j * 8192 + w * 1024);
        }
        const float cs0 = csq[k * NK + c * 64 + wn + l15];
        const float cs1 = csq[k * NK + c * 64 + wn + 16 + l15];
        f32x4 a1[2][2], a2[2][2];
#pragma unroll
        for (int mi = 0; mi < 2; ++mi) {
            a1[mi][0] = (f32x4){-0.5f * cs0, -0.5f * cs0, -0.5f * cs0, -0.5f * cs0};
            a1[mi][1] = (f32x4){-0.5f * cs1, -0.5f * cs1, -0.5f * cs1, -0.5f * cs1};
            a2[mi][0] = (f32x4){0.f, 0.f, 0.f, 0.f};
            a2[mi][1] = (f32x4){0.f, 0.f, 0.f, 0.f};
        }
#pragma unroll
        for (int kk = 0; kk < 4; ++kk) {
            const int kg = kk * 4 + l4;
            const int o0 = swz(wn + l15, kg), o1 = swz(wn + 16 + l15, kg);
            const f16x8 bh0 = *(const f16x8*)(bufc + o0);
            const f16x8 bh1 = *(const f16x8*)(bufc + o1);
            const f16x8 bl0 = *(const f16x8*)(bufc + 16384 + o0);
            const f16x8 bl1 = *(const f16x8*)(bufc + 16384 + o1);
#pragma unroll
            for (int mi = 0; mi < 2; ++mi) {
                a1[mi][0] = __builtin_amdgcn_mfma_f32_16x16x32_f16(Ah[mi][kk], bh0, a1[mi][0], 0, 0, 0);
                a1[mi][1] = __builtin_amdgcn_mfma_f32_16x16x32_f16(Ah[mi][kk], bh1, a1[mi][1], 0, 0, 0);
                a2[mi][0] = __builtin_amdgcn_mfma_f32_16x16x32_f16(Ah[mi][kk], bl0, a2[mi][0], 0, 0, 0);
                a2[mi][1] = __builtin_amdgcn_mfma_f32_16x16x32_f16(Ah[mi][kk], bl1, a2[mi][1], 0, 0, 0);
                a2[mi][0] = __builtin_amdgcn_mfma_f32_16x16x32_f16(Al[mi][kk], bh0, a2[mi][0], 0, 0, 0);
                a2[mi][1] = __builtin_amdgcn_mfma_f32_16x16x32_f16(Al[mi][kk], bh1, a2[mi][1], 0, 0, 0);
            }
        }
        // fused epilogue: s = a1 + a2/2048 ; track top-2 per owned row
        const int cb0 = c * 64 + wn + l15;
#pragma unroll
        for (int mi = 0; mi < 2; ++mi)
#pragma unroll
            for (int q = 0; q < 4; ++q) {
                const float s0 = fmaf(a2[mi][0][q], 4.8828125e-4f, a1[mi][0][q]);
                const float s1 = fmaf(a2[mi][1][q], 4.8828125e-4f, a1[mi][1][q]);
                float cv; int ci;
                if (s1 > s0) { cv = s1; ci = cb0 + 16; }
                else         { cv = s0; ci = cb0; }
                if (cv > rv1[mi][q]) {
                    rv2[mi][q] = rv1[mi][q]; ri2[mi][q] = ri1[mi][q];
                    rv1[mi][q] = cv;         ri1[mi][q] = ci;
                } else if (cv > rv2[mi][q]) {
                    rv2[mi][q] = cv; ri2[mi][q] = ci;
                }
            }
        asm volatile("s_waitcnt vmcnt(0)" ::: "memory");
        __syncthreads();
    }

    // cross-lane merge: 16 lanes of each lane-group share output rows
#pragma unroll
    for (int m = 1; m < 16; m <<= 1) {
#pragma unroll
        for (int mi = 0; mi < 2; ++mi)
#pragma unroll
            for (int q = 0; q < 4; ++q) {
                const float ov1 = __shfl_xor(rv1[mi][q], m, 16);
                const int   oi1 = __shfl_xor(ri1[mi][q], m, 16);
                const float ov2 = __shfl_xor(rv2[mi][q], m, 16);
                const int   oi2 = __shfl_xor(ri2[mi][q], m, 16);
                ins(ov1, oi1, rv1[mi][q], ri1[mi][q], rv2[mi][q], ri2[mi][q]);
                ins(ov2, oi2, rv1[mi][q], ri1[mi][q], rv2[mi][q], ri2[mi][q]);
            }
    }
    // cross-wave merge (col-halves wc=0/1 cover different codeword sets)
    if (l15 == 0) {
#pragma unroll
        for (int mi = 0; mi < 2; ++mi)
#pragma unroll
            for (int q = 0; q < 4; ++q) {
                const int row = wm + mi * 16 + l4 * 4 + q;
                int4 pkv;
                pkv.x = __float_as_int(rv1[mi][q]); pkv.y = ri1[mi][q];
                pkv.z = __float_as_int(rv2[mi][q]); pkv.w = ri2[mi][q];
                *(int4*)(lds + (wc * 128 + row) * 16) = pkv;
            }
    }
    __syncthreads();
    if (t < 128) {
        const int4 A  = *(const int4*)(lds + t * 16);
        const int4 Bv = *(const int4*)(lds + (128 + t) * 16);
        float v1 = __int_as_float(A.x); int i1 = A.y;
        float v2 = __int_as_float(A.z); int i2 = A.w;
        ins(__int_as_float(Bv.x), Bv.y, v1, i1, v2, i2);
        ins(__int_as_float(Bv.z), Bv.w, v1, i1, v2, i2);
        pk[(size_t)(bm * 128 + t) * NC + k] = (uint32_t)i1 | ((uint32_t)i2 << 16);
    }
}

// ---------------------------------------------------------------------------
// Kernel 3a: relocate packed entries into each row's header, for all rows
// NOT in [4300,4366). Reads all of P; writes only outside P's rows.
// ---------------------------------------------------------------------------
__global__ __launch_bounds__(512) void reloc_main(const uint32_t* __restrict__ pk,
                                                  uint32_t* __restrict__ hdr) {
    const int g = blockIdx.x * 512 + threadIdx.x;   // [0, 65536)
    const int b = g >> 3, k = g & 7;
    const uint32_t v = pk[g];
    if (b < TAIL_LO || b >= TAIL_HI) hdr[(size_t)b * NCLS + k] = v;
}

// ---------------------------------------------------------------------------
// Kernel 3b: relocate the 66 tail rows (the rows P itself occupies).
// Reads P entries at u32 idx [34400,34928) (row 4334 bytes [1600,3712));
// writes headers of rows 4300..4365 (bytes [0,32)) — disjoint. Runs AFTER
// reloc_main, so the entries it overwrites are already relocated.
// ---------------------------------------------------------------------------
__global__ __launch_bounds__(256) void reloc_tail(const uint32_t* __restrict__ pk,
                                                  uint32_t* __restrict__ hdr) {
    for (int g = threadIdx.x; g < (TAIL_HI - TAIL_LO) * 8; g += 256) {
        const int b = TAIL_LO + (g >> 3), k = g & 7;
        hdr[(size_t)b * NCLS + k] = pk[(size_t)b * 8 + k];
    }
}

// ---------------------------------------------------------------------------
// Kernel 4: per batch row — exact f64 re-rank of the packed top-2 (fused
// refine), then gather 8 table rows and sum. Reads ONLY its own row header,
// then overwrites its own row. No cross-block aliasing.
// ---------------------------------------------------------------------------
__global__ __launch_bounds__(256) void finish(const float* __restrict__ x,
                                              const float* __restrict__ cb,
                                              const float* __restrict__ tables,
                                              float* __restrict__ out) {
    const int b = blockIdx.x, t = threadIdx.x;
    const int lane = t & 63, w = t >> 6;
    __shared__ uint32_t hdr_s[8];
    __shared__ int rows_s[8];
    if (t < 8) hdr_s[t] = ((const uint32_t*)out)[(size_t)b * NCLS + t];
    __syncthreads();
#pragma unroll
    for (int kq = 0; kq < 2; ++kq) {
        const int k = w * 2 + kq;
        const uint32_t h = hdr_s[k];
        const int i1 = (int)(h & 0xFFFFu), i2 = (int)(h >> 16);
        const float x0 = x[(size_t)b * 1024 + k * 128 + lane];
        const float x1 = x[(size_t)b * 1024 + k * 128 + 64 + lane];
        const float* c1p = cb + ((size_t)k * NK + i1) * DD;
        const float* c2p = cb + ((size_t)k * NK + i2) * DD;
        const float c10 = c1p[lane], c11 = c1p[64 + lane];
        const float c20 = c2p[lane], c21 = c2p[64 + lane];
        double d1 = (double)c10 * c10 - 2.0 * (double)x0 * c10
                  + (double)c11 * c11 - 2.0 * (double)x1 * c11;
        double d2 = (double)c20 * c20 - 2.0 * (double)x0 * c20
                  + (double)c21 * c21 - 2.0 * (double)x1 * c21;
#pragma unroll
        for (int m = 32; m >= 1; m >>= 1) {
            d1 += __shfl_xor(d1, m, 64);
            d2 += __shfl_xor(d2, m, 64);
        }
        if (lane == 0)
            rows_s[k] = (d1 < d2) ? i1 : (d2 < d1 ? i2 : (i1 < i2 ? i1 : i2));
    }
    __syncthreads();
    if (t < 250) {
        float4 acc = {0.f, 0.f, 0.f, 0.f};
#pragma unroll
        for (int k = 0; k < NC; ++k) {
            const float4 v =
                *((const float4*)(tables + ((size_t)k * NK + rows_s[k]) * NCLS) + t);
            acc.x += v.x; acc.y += v.y; acc.z += v.z; acc.w += v.w;
        }
        *((float4*)(out + (size_t)b * NCLS) + t) = acc;
    }
}

extern "C" void kernel_launch(void* const* d_in, const int* in_sizes, int n_in,
                              void* d_out, int out_size, void* d_ws, size_t ws_size,
                              hipStream_t stream) {
    const float* x      = (const float*)d_in[0];
    const float* cb     = (const float*)d_in[1];
    const float* tables = (const float*)d_in[2];
    float* out = (float*)d_out;

    // Everything lives in d_out; d_ws is never touched (ws_size may be 0).
    char*     bimg = (char*)d_out;
    float*    csq  = (float*)d_out + CSQ_F32;
    uint32_t* pk   = (uint32_t*)d_out + P_U32;
    uint32_t* hdr  = (uint32_t*)d_out;

    prep_cb<<<dim3(64, NC), 256, 0, stream>>>(cb, bimg, csq);
    gemm_argmin<<<dim3(64, NC), 512, 0, stream>>>(x, bimg, csq, pk);
    reloc_main<<<128, 512, 0, stream>>>(pk, hdr);
    reloc_tail<<<1, 256, 0, stream>>>(pk, hdr);
    finish<<<NB, 256, 0, stream>>>(x, cb, tables, out);
}

// Round 3
// 483.642 us; speedup vs baseline: 1.8004x; 1.8004x over previous
//
#include <hip/hip_runtime.h>
#include <stdint.h>

#define NC   8
#define NK   4096
#define DD   128
#define NCLS 1000
#define NB   8192

// ---------------------------------------------------------------------------
// d_out byte layout during the run (out buffer = 32,768,000 B total):
//   [0,          16,777,216)  bimg : prepped f16 hi/lo codebook images
//   [16,777,216, 16,908,288)  csq  : f32 ||c||^2  (8*4096)
//   [17,200,000, 17,462,144)  P    : packed top-2 (u16|u16) per (b,k)
//   reloc_* copy each row's 8 packed u32s into that row's first 32 bytes.
//   finish reads ONLY its own row header, then overwrites the full row.
//   d_ws is never used (ws_size may be 0).
// ---------------------------------------------------------------------------
#define CSQ_F32   4194304
#define P_U32     4300000
#define TAIL_LO   4300
#define TAIL_HI   4366

typedef _Float16 f16;
typedef f16   f16x8 __attribute__((ext_vector_type(8)));
typedef float f32x4 __attribute__((ext_vector_type(4)));

typedef const __attribute__((address_space(1))) unsigned int g_u32;
typedef __attribute__((address_space(3))) unsigned int l_u32;

__device__ __forceinline__ void gll16(const char* g, char* l) {
    __builtin_amdgcn_global_load_lds((g_u32*)g, (l_u32*)l, 16, 0, 0);
}

// XOR swizzle within an 8KB half-chunk: [32 rows][256B], bank-spread reads.
__device__ __forceinline__ int swz(int row, int kg) {
    return (row * 256 + kg * 16) ^ ((row & 7) << 4);
}

__device__ __forceinline__ void ins(float cv, int ci, float& v1, int& i1,
                                    float& v2, int& i2) {
    const bool b1 = (cv > v1) || (cv == v1 && ci < i1);
    const bool b2 = (cv > v2) || (cv == v2 && ci < i2);
    if (b1) { v2 = v1; i2 = i1; v1 = cv; i1 = ci; }
    else if (b2) { v2 = cv; i2 = ci; }
}

__device__ __forceinline__ void cvt8(const float4 v0, const float4 v1,
                                     f16x8& h, f16x8& l) {
    float vs[8] = {v0.x, v0.y, v0.z, v0.w, v1.x, v1.y, v1.z, v1.w};
#pragma unroll
    for (int i = 0; i < 8; ++i) {
        const float v = vs[i];
        const f16 hi = (f16)v;
        h[i] = hi;
        l[i] = (f16)((v - (float)hi) * 2048.0f);
    }
}

// ---------------------------------------------------------------------------
// Kernel 1: split codebooks into f16 hi/lo pre-swizzled LDS images + csq.
// Image per (k, group of 64 codewords): 32KB = [hi 16KB][lo 16KB].
// ---------------------------------------------------------------------------
__global__ __launch_bounds__(256) void prep_cb(const float* __restrict__ cb,
                                               char* __restrict__ bimg,
                                               float* __restrict__ csq) {
    const int chunk = blockIdx.x, k = blockIdx.y, t = threadIdx.x;
    const float* src = cb + ((size_t)k * NK + (size_t)chunk * 64) * DD;
    char* dst = bimg + (size_t)(k * 64 + chunk) * 32768;
#pragma unroll
    for (int j = 0; j < 4; ++j) {
        const int col = j * 16 + (t >> 4);
        const int kg  = t & 15;
        const float* p = src + (size_t)col * DD + kg * 8;
        const float4 v0 = *(const float4*)p;
        const float4 v1 = *(const float4*)(p + 4);
        float vs[8] = {v0.x, v0.y, v0.z, v0.w, v1.x, v1.y, v1.z, v1.w};
        f16x8 h, l;
        float ss = 0.f;
#pragma unroll
        for (int i = 0; i < 8; ++i) {
            const float v = vs[i];
            ss += v * v;
            const f16 hi = (f16)v;
            h[i] = hi;
            l[i] = (f16)((v - (float)hi) * 2048.0f);
        }
#pragma unroll
        for (int m = 1; m < 16; m <<= 1) ss += __shfl_xor(ss, m, 16);
        if (kg == 0) csq[k * NK + chunk * 64 + col] = ss;
        const int r = col & 31;   // swz within the 8KB half (rows 0..31)
        const int half = col >> 5;
        const int off = half * 8192 + swz(r, kg);
        *(f16x8*)(dst + off)         = h;
        *(f16x8*)(dst + 16384 + off) = l;
    }
}

// ---------------------------------------------------------------------------
// One pipelined chunk step of the GEMM: counted vmcnt + raw barrier (T4),
// issue chunk c+2, compute chunk c (24 MFMAs/wave), fused top-2 epilogue.
// ---------------------------------------------------------------------------
template <int W, bool ISS>
__device__ __forceinline__ void chunk_step(
    int c, int& bcur, int& bnx, char* lds, const char* gB,
    int w, int lane, int l15,
    const f16x8 (&Ah)[4], const f16x8 (&Al)[4], const int (&boff)[4][2],
    float (&rv1)[4], float (&rv2)[4], int (&ri1)[4], int (&ri2)[4]) {

    asm volatile("s_waitcnt vmcnt(%0)" :: "i"(W) : "memory");
    __builtin_amdgcn_s_barrier();

    if (ISS) {
        const int cn = c + 2;
        const char* src = gB + (size_t)(cn >> 1) * 32768 + (size_t)(cn & 1) * 8192;
        char* dstb = lds + bnx * 16384 + w * 1024;
        gll16(src + w * 1024 + lane * 16, dstb);
        gll16(src + 16384 + w * 1024 + lane * 16, dstb + 8192);
    }

    char* bufc = lds + bcur * 16384;
    const float cs0 = *(const float*)(lds + 49152 + (c * 32 + l15) * 4);
    const float cs1 = *(const float*)(lds + 49152 + (c * 32 + 16 + l15) * 4);
    f32x4 a10 = (f32x4){-0.5f * cs0, -0.5f * cs0, -0.5f * cs0, -0.5f * cs0};
    f32x4 a11 = (f32x4){-0.5f * cs1, -0.5f * cs1, -0.5f * cs1, -0.5f * cs1};
    f32x4 a20 = (f32x4){0.f, 0.f, 0.f, 0.f};
    f32x4 a21 = (f32x4){0.f, 0.f, 0.f, 0.f};

    __builtin_amdgcn_s_setprio(1);
#pragma unroll
    for (int kk = 0; kk < 4; ++kk) {
        const f16x8 bh0 = *(const f16x8*)(bufc + boff[kk][0]);
        const f16x8 bh1 = *(const f16x8*)(bufc + boff[kk][1]);
        const f16x8 bl0 = *(const f16x8*)(bufc + 8192 + boff[kk][0]);
        const f16x8 bl1 = *(const f16x8*)(bufc + 8192 + boff[kk][1]);
        a10 = __builtin_amdgcn_mfma_f32_16x16x32_f16(Ah[kk], bh0, a10, 0, 0, 0);
        a11 = __builtin_amdgcn_mfma_f32_16x16x32_f16(Ah[kk], bh1, a11, 0, 0, 0);
        a20 = __builtin_amdgcn_mfma_f32_16x16x32_f16(Ah[kk], bl0, a20, 0, 0, 0);
        a21 = __builtin_amdgcn_mfma_f32_16x16x32_f16(Ah[kk], bl1, a21, 0, 0, 0);
        a20 = __builtin_amdgcn_mfma_f32_16x16x32_f16(Al[kk], bh0, a20, 0, 0, 0);
        a21 = __builtin_amdgcn_mfma_f32_16x16x32_f16(Al[kk], bh1, a21, 0, 0, 0);
    }
    __builtin_amdgcn_s_setprio(0);

    const int col0 = c * 32 + l15;
#pragma unroll
    for (int q = 0; q < 4; ++q) {
        const float s0 = fmaf(a20[q], 4.8828125e-4f, a10[q]);
        const float s1 = fmaf(a21[q], 4.8828125e-4f, a11[q]);
        float cv; int ci;
        if (s1 > s0) { cv = s1; ci = col0 + 16; }
        else         { cv = s0; ci = col0; }
        if (cv > rv1[q]) {
            rv2[q] = rv1[q]; ri2[q] = ri1[q];
            rv1[q] = cv;     ri1[q] = ci;
        } else if (cv > rv2[q]) {
            rv2[q] = cv; ri2[q] = ci;
        }
    }
    bcur = (bcur == 2) ? 0 : bcur + 1;
    bnx  = (bnx  == 2) ? 0 : bnx  + 1;
}

// ---------------------------------------------------------------------------
// Kernel 2: fused split-f16 MFMA distance GEMM + top-2 argmax of
// s = dot(x,c) - csq/2. Block: 128 rows x one codebook, 512 threads,
// 8 waves each owning 16 rows x 32 codewords per chunk. 3-buffer
// counted-vmcnt pipeline; A-frags direct global->reg; csq in LDS.
// LDS 64KB -> 2 blocks/CU -> 4 waves/SIMD.
// ---------------------------------------------------------------------------
__global__ __launch_bounds__(512, 4) void gemm_argmin(
    const float* __restrict__ x, const char* __restrict__ bimg,
    const float* __restrict__ csq_g, uint32_t* __restrict__ pk) {
    __shared__ char lds[65536];
    const int t = threadIdx.x;
    const int lane = t & 63, w = t >> 6;
    const int bm = blockIdx.x, k = blockIdx.y;
    const int l15 = lane & 15, l4 = lane >> 4;

    // csq -> LDS [49152, 65536)
    {
        const float4* cg = (const float4*)(csq_g + k * NK);
        float4* cl = (float4*)(lds + 49152);
        cl[t] = cg[t];
        cl[t + 512] = cg[t + 512];
    }

    // A fragments: direct global f32 -> split f16 hi/lo in registers.
    // Wave w owns rows [bm*128 + w*16, +16); lane l15 = row-in-16,
    // l4 = k-quad; element k-range = (kk*4+l4)*8 .. +8.
    f16x8 Ah[4], Al[4];
    {
        const float* xrow = x + (size_t)(bm * 128 + w * 16 + l15) * 1024 + k * DD;
#pragma unroll
        for (int kk = 0; kk < 4; ++kk) {
            const float* p = xrow + (kk * 4 + l4) * 8;
            cvt8(*(const float4*)p, *(const float4*)(p + 4), Ah[kk], Al[kk]);
        }
    }

    // Precompute swizzled B-read offsets (chunk-independent).
    int boff[4][2];
#pragma unroll
    for (int kk = 0; kk < 4; ++kk) {
#pragma unroll
        for (int n = 0; n < 2; ++n)
            boff[kk][n] = swz(n * 16 + l15, kk * 4 + l4);
    }

    float rv1[4], rv2[4];
    int   ri1[4], ri2[4];
#pragma unroll
    for (int q = 0; q < 4; ++q) {
        rv1[q] = -3.402823466e38f; rv2[q] = -3.402823466e38f;
        ri1[q] = 0; ri2[q] = 0;
    }

    __syncthreads();   // csq visible; drains A loads (vmcnt clean)

    const char* gB = bimg + (size_t)k * 64 * 32768;
    // prologue: issue chunks 0 and 1
#pragma unroll
    for (int cn = 0; cn < 2; ++cn) {
        const char* src = gB + (size_t)(cn >> 1) * 32768 + (size_t)(cn & 1) * 8192;
        char* dstb = lds + cn * 16384 + w * 1024;
        gll16(src + w * 1024 + lane * 16, dstb);
        gll16(src + 16384 + w * 1024 + lane * 16, dstb + 8192);
    }

    int bcur = 0, bnx = 2;
#pragma unroll 1
    for (int c = 0; c < 126; ++c)
        chunk_step<2, true>(c, bcur, bnx, lds, gB, w, lane, l15,
                            Ah, Al, boff, rv1, rv2, ri1, ri2);
    chunk_step<2, false>(126, bcur, bnx, lds, gB, w, lane, l15,
                         Ah, Al, boff, rv1, rv2, ri1, ri2);
    chunk_step<0, false>(127, bcur, bnx, lds, gB, w, lane, l15,
                         Ah, Al, boff, rv1, rv2, ri1, ri2);

    // cross-lane merge: 16 lanes of each l15-group share output rows.
#pragma unroll
    for (int m = 1; m < 16; m <<= 1) {
#pragma unroll
        for (int q = 0; q < 4; ++q) {
            const float ov1 = __shfl_xor(rv1[q], m, 16);
            const int   oi1 = __shfl_xor(ri1[q], m, 16);
            const float ov2 = __shfl_xor(rv2[q], m, 16);
            const int   oi2 = __shfl_xor(ri2[q], m, 16);
            ins(ov1, oi1, rv1[q], ri1[q], rv2[q], ri2[q]);
            ins(ov2, oi2, rv1[q], ri1[q], rv2[q], ri2[q]);
        }
    }
    // waves own disjoint rows -> no cross-wave merge needed.
    if (l15 == 0) {
#pragma unroll
        for (int q = 0; q < 4; ++q) {
            const int row = bm * 128 + w * 16 + l4 * 4 + q;
            pk[(size_t)row * NC + k] =
                (uint32_t)ri1[q] | ((uint32_t)ri2[q] << 16);
        }
    }
}

// ---------------------------------------------------------------------------
// Kernel 3a: relocate packed entries into each row's header, for all rows
// NOT in [4300,4366).
// ---------------------------------------------------------------------------
__global__ __launch_bounds__(512) void reloc_main(const uint32_t* __restrict__ pk,
                                                  uint32_t* __restrict__ hdr) {
    const int g = blockIdx.x * 512 + threadIdx.x;   // [0, 65536)
    const int b = g >> 3, k = g & 7;
    const uint32_t v = pk[g];
    if (b < TAIL_LO || b >= TAIL_HI) hdr[(size_t)b * NCLS + k] = v;
}

// ---------------------------------------------------------------------------
// Kernel 3b: relocate the 66 tail rows (the rows P itself occupies).
// Runs AFTER reloc_main; writes (row headers, bytes [0,32)) are disjoint
// from its reads (P at bytes [1600,3712) of row 4334 region).
// ---------------------------------------------------------------------------
__global__ __launch_bounds__(256) void reloc_tail(const uint32_t* __restrict__ pk,
                                                  uint32_t* __restrict__ hdr) {
    for (int g = threadIdx.x; g < (TAIL_HI - TAIL_LO) * 8; g += 256) {
        const int b = TAIL_LO + (g >> 3), k = g & 7;
        hdr[(size_t)b * NCLS + k] = pk[(size_t)b * 8 + k];
    }
}

// ---------------------------------------------------------------------------
// Kernel 4: per batch row — exact f64 re-rank of the packed top-2, then
// gather 8 table rows and sum. Reads ONLY its own row header, then
// overwrites its own row.
// ---------------------------------------------------------------------------
__global__ __launch_bounds__(256) void finish(const float* __restrict__ x,
                                              const float* __restrict__ cb,
                                              const float* __restrict__ tables,
                                              float* __restrict__ out) {
    const int b = blockIdx.x, t = threadIdx.x;
    const int lane = t & 63, w = t >> 6;
    __shared__ uint32_t hdr_s[8];
    __shared__ int rows_s[8];
    if (t < 8) hdr_s[t] = ((const uint32_t*)out)[(size_t)b * NCLS + t];
    __syncthreads();
#pragma unroll
    for (int kq = 0; kq < 2; ++kq) {
        const int k = w * 2 + kq;
        const uint32_t h = hdr_s[k];
        const int i1 = (int)(h & 0xFFFFu), i2 = (int)(h >> 16);
        const float x0 = x[(size_t)b * 1024 + k * 128 + lane];
        const float x1 = x[(size_t)b * 1024 + k * 128 + 64 + lane];
        const float* c1p = cb + ((size_t)k * NK + i1) * DD;
        const float* c2p = cb + ((size_t)k * NK + i2) * DD;
        const float c10 = c1p[lane], c11 = c1p[64 + lane];
        const float c20 = c2p[lane], c21 = c2p[64 + lane];
        double d1 = (double)c10 * c10 - 2.0 * (double)x0 * c10
                  + (double)c11 * c11 - 2.0 * (double)x1 * c11;
        double d2 = (double)c20 * c20 - 2.0 * (double)x0 * c20
                  + (double)c21 * c21 - 2.0 * (double)x1 * c21;
#pragma unroll
        for (int m = 32; m >= 1; m >>= 1) {
            d1 += __shfl_xor(d1, m, 64);
            d2 += __shfl_xor(d2, m, 64);
        }
        if (lane == 0)
            rows_s[k] = (d1 < d2) ? i1 : (d2 < d1 ? i2 : (i1 < i2 ? i1 : i2));
    }
    __syncthreads();
    if (t < 250) {
        float4 acc = {0.f, 0.f, 0.f, 0.f};
#pragma unroll
        for (int k = 0; k < NC; ++k) {
            const float4 v =
                *((const float4*)(tables + ((size_t)k * NK + rows_s[k]) * NCLS) + t);
            acc.x += v.x; acc.y += v.y; acc.z += v.z; acc.w += v.w;
        }
        *((float4*)(out + (size_t)b * NCLS) + t) = acc;
    }
}

extern "C" void kernel_launch(void* const* d_in, const int* in_sizes, int n_in,
                              void* d_out, int out_size, void* d_ws, size_t ws_size,
                              hipStream_t stream) {
    const float* x      = (const float*)d_in[0];
    const float* cb     = (const float*)d_in[1];
    const float* tables = (const float*)d_in[2];
    float* out = (float*)d_out;

    // Everything lives in d_out; d_ws is never touched.
    char*     bimg = (char*)d_out;
    float*    csq  = (float*)d_out + CSQ_F32;
    uint32_t* pk   = (uint32_t*)d_out + P_U32;
    uint32_t* hdr  = (uint32_t*)d_out;

    prep_cb<<<dim3(64, NC), 256, 0, stream>>>(cb, bimg, csq);
    gemm_argmin<<<dim3(64, NC), 512, 0, stream>>>(x, bimg, csq, pk);
    reloc_main<<<128, 512, 0, stream>>>(pk, hdr);
    reloc_tail<<<1, 256, 0, stream>>>(pk, hdr);
    finish<<<NB, 256, 0, stream>>>(x, cb, tables, out);
}